// Round 3
// baseline (1203.966 us; speedup 1.0000x reference)
//
#include <hip/hip_runtime.h>
#include <hip/hip_bf16.h>

#define M_TOT 8192
#define N_TOT 16384
#define K_TOT 4096
#define BM 256
#define BN 256
#define BK 64
#define NT (K_TOT / BK)  // 64 K-tiles

typedef __bf16 bf16x8 __attribute__((ext_vector_type(8)));
typedef float f32x4 __attribute__((ext_vector_type(4)));

#define GLOAD_LDS16(g, l)                                                     \
  __builtin_amdgcn_global_load_lds(                                           \
      (__attribute__((address_space(1))) const void*)(g),                     \
      (__attribute__((address_space(3))) void*)(l), 16, 0, 0)

__device__ __forceinline__ ushort f2bf_rne(float f) {
  unsigned u = __float_as_uint(f);
  u += 0x7FFFu + ((u >> 16) & 1u);
  return (ushort)(u >> 16);
}

__device__ __forceinline__ ushort sgn_bf16(float w) {
  return w > 0.f ? (ushort)0x3F80u : (w < 0.f ? (ushort)0xBF80u : (ushort)0u);
}

// ---------------- conversion kernels (pass 1) ----------------

__global__ void convert_x_kernel(const float* __restrict__ x,
                                 ushort* __restrict__ xb, int n4) {
  int i = blockIdx.x * blockDim.x + threadIdx.x;
  int stride = gridDim.x * blockDim.x;
  for (; i < n4; i += stride) {
    float4 v = ((const float4*)x)[i];
    ushort4 o;
    o.x = f2bf_rne(v.x);
    o.y = f2bf_rne(v.y);
    o.z = f2bf_rne(v.z);
    o.w = f2bf_rne(v.w);
    ((ushort4*)xb)[i] = o;
  }
}

__global__ void convert_w_kernel(const float* __restrict__ w,
                                 ushort* __restrict__ wb, int n4) {
  int i = blockIdx.x * blockDim.x + threadIdx.x;
  int stride = gridDim.x * blockDim.x;
  for (; i < n4; i += stride) {
    float4 v = ((const float4*)w)[i];
    ushort4 o;
    o.x = sgn_bf16(v.x);
    o.y = sgn_bf16(v.y);
    o.z = sgn_bf16(v.z);
    o.w = sgn_bf16(v.w);
    ((ushort4*)wb)[i] = o;
  }
}

// ---------------- 256x256 8-phase bf16 GEMM (T2+T3+T4+T5) ----------------
// C[m][n] = sum_k A[m][k] * B[n][k] + bias[n]   (B is row-major N x K = B^T)
// 512 threads = 8 waves (2M x 4N). BK=64 split into 2 K-slices of 32.
// LDS: [2 buf][2 ks][2 op][256 rows x 32 cols bf16] = 128 KiB.
//
// T2 swizzle (derived for 64B rows): item (row, chunk c; chunks are 16B)
// stored at byte = row*64 + (c ^ ((row>>1)&3))*16. gload_lds dest stays
// LINEAR; the permutation is applied to the per-lane GLOBAL source chunk
// (both-sides involution, rule 21). Frag-read bank-quad becomes
// 4*(fr&1) + (((fr>>1)&3) ^ hi) -> each quad hit exactly 2x per 16-lane
// group = free (m136). Source coalescing unchanged (permutes within 64B).
//
// Stage cadence per tile t (phases p0..p3):
//   p0 reads {A-ks0 mh0, B-ks0}; stages (t+1).A-ks1
//   p1 reads {A-ks0 mh1};        stages (t+2).B-ks0
//   p2 reads {A-ks1 mh0, B-ks1}; stages (t+2).A-ks0
//   p3 reads {A-ks1 mh1};        stages (t+2).B-ks1
//   p3 tail: s_waitcnt vmcnt(6)  -> tile t+1 fully landed

__global__ __launch_bounds__(512, 2) void gemm_bf16_8phase(
    const ushort* __restrict__ A, const ushort* __restrict__ B,
    const float* __restrict__ bias, float* __restrict__ C) {
  __shared__ ushort lds[2][2][2][8192];  // [buf][ks][op: 0=A 1=B][16KB half]

  int nwg = gridDim.x;  // 2048, divisible by 8
  int bid = blockIdx.x;
  int wg = (bid & 7) * (nwg >> 3) + (bid >> 3);  // XCD-bijective swizzle
  int bm = wg / (N_TOT / BN);
  int bn = wg % (N_TOT / BN);
  int rowBase = bm * BM;
  int colBase = bn * BN;

  int t = threadIdx.x;
  int lane = t & 63;
  int wave = t >> 6;
  int wr = wave >> 2;  // 0..1 -> M half
  int wc = wave & 3;   // 0..3 -> N quarter
  int fr = lane & 15;
  int hi = lane >> 4;

  // staging source: thread t owns LDS slot t (16B). Slot t = (row t>>2,
  // slot-chunk t&3). Stored item chunk = (t&3) ^ ((t>>3)&3)  [T2 involution].
  int sc = ((t & 3) ^ ((t >> 3) & 3)) * 8;  // ushort col offset
  const ushort* gA0 = A + (size_t)(rowBase + (t >> 2)) * K_TOT + sc;
  const ushort* gA1 = gA0 + (size_t)128 * K_TOT;  // +128 rows: XOR idx invariant
  const ushort* gB0 = B + (size_t)(colBase + (t >> 2)) * K_TOT + sc;
  const ushort* gB1 = gB0 + (size_t)128 * K_TOT;

  // frag-read offsets with matching XOR (row bases are multiples of 16 rows,
  // so the XOR index depends only on fr bits -> per-thread constant)
  int kx = (hi ^ ((fr >> 1) & 3)) * 8;       // swizzled K-chunk (ushorts)
  int aoff = (wr * 128 + fr) * 32 + kx;      // ushort offset in A half
  int boff = (wc * 64 + fr) * 32 + kx;       // ushort offset in B half
  int lt = t * 8;                            // staging dest (ushort units)

  f32x4 acc[8][4] = {};

#define STAGE_A(ks_, kt_)                                                     \
  {                                                                           \
    size_t _o = (size_t)(kt_) * 64 + (ks_) * 32;                              \
    GLOAD_LDS16(gA0 + _o, &lds[(kt_) & 1][ks_][0][lt]);                       \
    GLOAD_LDS16(gA1 + _o, &lds[(kt_) & 1][ks_][0][4096 + lt]);                \
  }
#define STAGE_B(ks_, kt_)                                                     \
  {                                                                           \
    size_t _o = (size_t)(kt_) * 64 + (ks_) * 32;                              \
    GLOAD_LDS16(gB0 + _o, &lds[(kt_) & 1][ks_][1][lt]);                       \
    GLOAD_LDS16(gB1 + _o, &lds[(kt_) & 1][ks_][1][4096 + lt]);                \
  }

#define PHASE(ks_, mh_, READB, STAGE_STMT, TAIL_STMT)                         \
  {                                                                           \
    const ushort* _ab = &lds[b][ks_][0][0];                                   \
    _Pragma("unroll") for (int mi = 0; mi < 4; ++mi)                          \
        af[mi] = *(const bf16x8*)(_ab + aoff + ((mh_)*64 + mi * 16) * 32);    \
    if (READB) {                                                              \
      const ushort* _bb = &lds[b][ks_][1][0];                                 \
      _Pragma("unroll") for (int ni = 0; ni < 4; ++ni)                        \
          bfv[ni] = *(const bf16x8*)(_bb + boff + ni * 512);                  \
    }                                                                         \
    STAGE_STMT;                                                               \
    __builtin_amdgcn_s_barrier();                                             \
    __builtin_amdgcn_s_setprio(1);                                            \
    _Pragma("unroll") for (int mi = 0; mi < 4; ++mi)                          \
        _Pragma("unroll") for (int ni = 0; ni < 4; ++ni)                      \
            acc[(mh_)*4 + mi][ni] = __builtin_amdgcn_mfma_f32_16x16x32_bf16(  \
                af[mi], bfv[ni], acc[(mh_)*4 + mi][ni], 0, 0, 0);             \
    __builtin_amdgcn_s_setprio(0);                                            \
    TAIL_STMT;                                                                \
    __builtin_amdgcn_s_barrier();                                             \
  }

  // prologue: tile0 all 4 halves + tile1 {B-ks0, A-ks0, B-ks1}
  STAGE_B(0, 0);
  STAGE_A(0, 0);
  STAGE_B(1, 0);
  STAGE_A(1, 0);
  STAGE_B(0, 1);
  STAGE_A(0, 1);
  STAGE_B(1, 1);
  asm volatile("s_waitcnt vmcnt(6)" ::: "memory");  // tile0 landed
  __builtin_amdgcn_s_barrier();

  for (int tt = 0; tt < NT; ++tt) {
    int b = tt & 1;
    bf16x8 af[4], bfv[4];
    PHASE(0, 0, true, { if (tt + 1 < NT) STAGE_A(1, tt + 1); }, {});
    PHASE(0, 1, false, { if (tt + 2 < NT) STAGE_B(0, tt + 2); }, {});
    PHASE(1, 0, true, { if (tt + 2 < NT) STAGE_A(0, tt + 2); }, {});
    PHASE(1, 1, false, { if (tt + 2 < NT) STAGE_B(1, tt + 2); }, {
      if (tt + 2 < NT) {
        asm volatile("s_waitcnt vmcnt(6)" ::: "memory");
      } else if (tt + 1 < NT) {
        asm volatile("s_waitcnt vmcnt(0)" ::: "memory");
      }
    });
  }

#undef PHASE
#undef STAGE_A
#undef STAGE_B

  // epilogue: C/D layout col = fr, row = hi*4 + rg
#pragma unroll
  for (int mm = 0; mm < 8; ++mm) {
    int row0 = rowBase + wr * 128 + mm * 16 + hi * 4;
#pragma unroll
    for (int ni = 0; ni < 4; ++ni) {
      int col = colBase + wc * 64 + ni * 16 + fr;
      float bv = bias[col];
#pragma unroll
      for (int rg = 0; rg < 4; ++rg)
        C[(size_t)(row0 + rg) * N_TOT + col] = acc[mm][ni][rg] + bv;
    }
  }
}

// ---------------- fallback: fused fp32->bf16 conversion inside GEMM ----------

__global__ void gemm_fused_kernel(const float* __restrict__ A,
                                  const float* __restrict__ W,
                                  const float* __restrict__ bias,
                                  float* __restrict__ C) {
  __shared__ ushort lsA[128 * 32];
  __shared__ ushort lsB[128 * 32];

  int nwg = gridDim.x;
  int bid = blockIdx.x;
  int wg = (bid & 7) * (nwg >> 3) + (bid >> 3);
  const int NBN = N_TOT / 128;
  int bm = wg / NBN;
  int bn = wg % NBN;
  int rowBase = bm * 128;
  int colBase = bn * 128;

  int t = threadIdx.x;
  int lane = t & 63;
  int wave = t >> 6;
  int wm = (wave >> 1) * 64;
  int wn = (wave & 1) * 64;

  f32x4 acc[4][4] = {};

  int srow = t >> 3;
  int scol = (t & 7) * 4;
  int fr = lane & 15;
  int koff = (lane >> 4) * 8;

  for (int k0 = 0; k0 < K_TOT; k0 += 32) {
    float4 va[4], vb[4];
#pragma unroll
    for (int r = 0; r < 4; ++r) {
      va[r] = *(const float4*)&A[(size_t)(rowBase + r * 32 + srow) * K_TOT + k0 + scol];
      vb[r] = *(const float4*)&W[(size_t)(colBase + r * 32 + srow) * K_TOT + k0 + scol];
    }
    __syncthreads();
#pragma unroll
    for (int r = 0; r < 4; ++r) {
      int e = r * 1024 + t * 4;
      ushort4 oa, ob;
      oa.x = f2bf_rne(va[r].x); oa.y = f2bf_rne(va[r].y);
      oa.z = f2bf_rne(va[r].z); oa.w = f2bf_rne(va[r].w);
      ob.x = sgn_bf16(vb[r].x); ob.y = sgn_bf16(vb[r].y);
      ob.z = sgn_bf16(vb[r].z); ob.w = sgn_bf16(vb[r].w);
      *(ushort4*)&lsA[e] = oa;
      *(ushort4*)&lsB[e] = ob;
    }
    __syncthreads();

    bf16x8 af[4], bfr[4];
#pragma unroll
    for (int i = 0; i < 4; ++i)
      af[i] = *(const bf16x8*)&lsA[(wm + i * 16 + fr) * 32 + koff];
#pragma unroll
    for (int j = 0; j < 4; ++j)
      bfr[j] = *(const bf16x8*)&lsB[(wn + j * 16 + fr) * 32 + koff];

#pragma unroll
    for (int i = 0; i < 4; ++i)
#pragma unroll
      for (int j = 0; j < 4; ++j)
        acc[i][j] = __builtin_amdgcn_mfma_f32_16x16x32_bf16(af[i], bfr[j],
                                                            acc[i][j], 0, 0, 0);
  }

  int orow0 = rowBase + wm + ((lane >> 4) << 2);
  int ocol0 = colBase + wn + (lane & 15);
#pragma unroll
  for (int i = 0; i < 4; ++i) {
#pragma unroll
    for (int j = 0; j < 4; ++j) {
      int col = ocol0 + j * 16;
      float bv = bias[col];
#pragma unroll
      for (int rg = 0; rg < 4; ++rg) {
        int row = orow0 + i * 16 + rg;
        C[(size_t)row * N_TOT + col] = acc[i][j][rg] + bv;
      }
    }
  }
}

extern "C" void kernel_launch(void* const* d_in, const int* in_sizes, int n_in,
                              void* d_out, int out_size, void* d_ws,
                              size_t ws_size, hipStream_t stream) {
  const float* x = (const float*)d_in[0];
  const float* W = (const float*)d_in[1];
  const float* b = (const float*)d_in[2];
  float* out = (float*)d_out;

  const size_t xb_elems = (size_t)M_TOT * K_TOT;
  const size_t wb_elems = (size_t)N_TOT * K_TOT;
  const size_t need = (xb_elems + wb_elems) * sizeof(ushort);

  if (ws_size >= need) {
    ushort* xb = (ushort*)d_ws;
    ushort* wb = xb + xb_elems;
    convert_x_kernel<<<2048, 256, 0, stream>>>(x, xb, (int)(xb_elems / 4));
    convert_w_kernel<<<2048, 256, 0, stream>>>(W, wb, (int)(wb_elems / 4));
    const int nblocks = (M_TOT / BM) * (N_TOT / BN);  // 2048
    gemm_bf16_8phase<<<nblocks, 512, 0, stream>>>(xb, wb, b, out);
  } else {
    const int nblocks = (M_TOT / 128) * (N_TOT / 128);
    gemm_fused_kernel<<<nblocks, 256, 0, stream>>>(x, W, b, out);
  }
}

// Round 4
// 855.522 us; speedup vs baseline: 1.4073x; 1.4073x over previous
//
#include <hip/hip_runtime.h>
#include <hip/hip_bf16.h>

#define M_TOT 8192
#define N_TOT 16384
#define K_TOT 4096
#define BM 256
#define BN 256
#define BK 64
#define NT (K_TOT / BK)  // 64 K-tiles

typedef int i32x4 __attribute__((ext_vector_type(4)));
typedef int i32x16 __attribute__((ext_vector_type(16)));
typedef __bf16 bf16x8 __attribute__((ext_vector_type(8)));
typedef float f32x4 __attribute__((ext_vector_type(4)));

#define GLOAD_LDS16(g, l)                                                     \
  __builtin_amdgcn_global_load_lds(                                           \
      (__attribute__((address_space(1))) const void*)(g),                     \
      (__attribute__((address_space(3))) void*)(l), 16, 0, 0)

__device__ __forceinline__ ushort f2bf_rne(float f) {
  unsigned u = __float_as_uint(f);
  u += 0x7FFFu + ((u >> 16) & 1u);
  return (ushort)(u >> 16);
}
__device__ __forceinline__ ushort sgn_bf16(float w) {
  return w > 0.f ? (ushort)0x3F80u : (w < 0.f ? (ushort)0xBF80u : (ushort)0u);
}

// ---------------- pass 1a: per-row amax + quantize x to i8 (one read pass) ---
// block = one row (4096 floats = 1024 float4); 256 threads x 4 float4 each.
__global__ void quant_x_kernel(const float* __restrict__ x,
                               char* __restrict__ xq, float* __restrict__ s) {
  int row = blockIdx.x;
  const float4* xr = (const float4*)(x + (size_t)row * K_TOT);
  int tid = threadIdx.x;
  float4 v[4];
  float amax = 0.f;
#pragma unroll
  for (int j = 0; j < 4; ++j) {
    v[j] = xr[j * 256 + tid];
    amax = fmaxf(amax, fmaxf(fmaxf(fabsf(v[j].x), fabsf(v[j].y)),
                             fmaxf(fabsf(v[j].z), fabsf(v[j].w))));
  }
#pragma unroll
  for (int o = 32; o > 0; o >>= 1) amax = fmaxf(amax, __shfl_xor(amax, o));
  __shared__ float wmax[4];
  if ((tid & 63) == 0) wmax[tid >> 6] = amax;
  __syncthreads();
  amax = fmaxf(fmaxf(wmax[0], wmax[1]), fmaxf(wmax[2], wmax[3]));
  float inv = amax > 0.f ? 127.0f / amax : 0.f;
  if (tid == 0) s[row] = amax * (1.0f / 127.0f);
  int* out = (int*)(xq + (size_t)row * K_TOT);
#pragma unroll
  for (int j = 0; j < 4; ++j) {
    int q0 = max(-127, min(127, __float2int_rn(v[j].x * inv)));
    int q1 = max(-127, min(127, __float2int_rn(v[j].y * inv)));
    int q2 = max(-127, min(127, __float2int_rn(v[j].z * inv)));
    int q3 = max(-127, min(127, __float2int_rn(v[j].w * inv)));
    out[j * 256 + tid] =
        (q0 & 255) | ((q1 & 255) << 8) | ((q2 & 255) << 16) | ((q3 & 255) << 24);
  }
}

// ---------------- pass 1b: W -> sign in i8 ----------------
__global__ void quant_w_kernel(const float* __restrict__ w,
                               char* __restrict__ wq, int n4) {
  int i = blockIdx.x * blockDim.x + threadIdx.x;
  int stride = gridDim.x * blockDim.x;
  for (; i < n4; i += stride) {
    float4 v = ((const float4*)w)[i];
    int q0 = v.x > 0.f ? 1 : (v.x < 0.f ? -1 : 0);
    int q1 = v.y > 0.f ? 1 : (v.y < 0.f ? -1 : 0);
    int q2 = v.z > 0.f ? 1 : (v.z < 0.f ? -1 : 0);
    int q3 = v.w > 0.f ? 1 : (v.w < 0.f ? -1 : 0);
    ((int*)wq)[i] =
        (q0 & 255) | ((q1 & 255) << 8) | ((q2 & 255) << 16) | ((q3 & 255) << 24);
  }
}

// ---------------- pass 2: i8 GEMM, mfma_i32_32x32x32_i8, 2-phase/tile --------
// C[m][n] = s[m] * (sum_k A8[m][k]*W8[n][k]) + bias[n]   (i32 accum, exact)
// 512 threads = 8 waves (2M x 4N); per-wave out 128x64 = 4 m-tiles x 2 n-tiles
// of 32x32. BK=64 = 2 ks-slices of K=32.
// LDS: [2 buf][2 ks][2 op][256 rows x 32B] = 64 KiB.
// Swizzle: 16B chunk c of row r stored at slot c ^ ((r>>2)&1)  (both-sides:
// pre-swizzled global source + swizzled read; gload_lds dest linear).
// Bank check: quad = (2*(l&31) + c') & 7 -> 8 lanes/quad uniform = min-cycles.
// Frag (32x32x32 i8): A row = lane&31, k = (lane>>5)*16 + j; C/D col = lane&31,
// row = (reg&3) + 8*(reg>>2) + 4*(lane>>5)  [m74/m101, dtype-independent].
// Cadence per tile t (buf b=t&1):
//   P0(ks0): read A[4]+B[2] frags; stage ks1(t+1) [2 loads]; bar; 8 MFMA; bar
//   P1(ks1): read A[4]+B[2];       stage ks0(t+2) [2 loads]; bar; 8 MFMA;
//            vmcnt(2); bar      (oldest 4 = all of tile t+1 landed)
// Slab lifetimes: each slab read in exactly ONE phase; every overwriting stage
// issues after a barrier that follows the lgkm-drained last read of that slab.
__global__ __launch_bounds__(512, 2) void gemm_i8_2phase(
    const char* __restrict__ A, const char* __restrict__ B,
    const float* __restrict__ s, const float* __restrict__ bias,
    float* __restrict__ C) {
  __shared__ char lds[2][2][2][8192];  // [buf][ks][op 0=A 1=B][256x32B slab]

  int nwg = gridDim.x;  // 2048, divisible by 8
  int bid = blockIdx.x;
  int wg = (bid & 7) * (nwg >> 3) + (bid >> 3);  // XCD-bijective swizzle
  int bm = wg / (N_TOT / BN);
  int bn = wg % (N_TOT / BN);
  int rowBase = bm * BM;
  int colBase = bn * BN;

  int t = threadIdx.x;
  int lane = t & 63;
  int wave = t >> 6;
  int wr = wave >> 2;  // M half (128)
  int wc = wave & 3;   // N quarter (64)
  int l31 = lane & 31;
  int hi = lane >> 5;

  // staging: thread t owns 16B slot at byte t*16 = (row t>>1, slot-chunk t&1);
  // stored item chunk = (t&1) ^ ((row>>2)&1) = (t&1) ^ ((t>>3)&1)
  int sc = ((t & 1) ^ ((t >> 3) & 1)) * 16;
  const char* gA = A + (size_t)(rowBase + (t >> 1)) * K_TOT + sc;
  const char* gB = B + (size_t)(colBase + (t >> 1)) * K_TOT + sc;
  int lt = t * 16;

  // frag read: chunk wanted = hi; stored at hi ^ ((row>>2)&1); row bases are
  // multiples of 32 so (row>>2)&1 = (lane>>2)&1 -> per-lane constant.
  int csw = (hi ^ ((lane >> 2) & 1)) * 16;
  int aoff = (wr * 128 + l31) * 32 + csw;
  int boff = (wc * 64 + l31) * 32 + csw;

  i32x16 acc[4][2] = {};

#define STAGE_A(ks_, kt_)                                                     \
  GLOAD_LDS16(gA + (size_t)(kt_)*64 + (ks_)*32, &lds[(kt_)&1][ks_][0][lt])
#define STAGE_B(ks_, kt_)                                                     \
  GLOAD_LDS16(gB + (size_t)(kt_)*64 + (ks_)*32, &lds[(kt_)&1][ks_][1][lt])

#define PHASE(ks_, STAGE_STMT, TAIL_STMT)                                     \
  {                                                                           \
    const char* _ab = &lds[b][ks_][0][0];                                     \
    const char* _bb = &lds[b][ks_][1][0];                                     \
    i32x4 af[4], bf[2];                                                       \
    _Pragma("unroll") for (int mi = 0; mi < 4; ++mi)                          \
        af[mi] = *(const i32x4*)(_ab + aoff + mi * 1024);                     \
    _Pragma("unroll") for (int ni = 0; ni < 2; ++ni)                          \
        bf[ni] = *(const i32x4*)(_bb + boff + ni * 1024);                     \
    STAGE_STMT;                                                               \
    __builtin_amdgcn_s_barrier();                                             \
    __builtin_amdgcn_s_setprio(1);                                            \
    _Pragma("unroll") for (int mi = 0; mi < 4; ++mi)                          \
        _Pragma("unroll") for (int ni = 0; ni < 2; ++ni)                      \
            acc[mi][ni] = __builtin_amdgcn_mfma_i32_32x32x32_i8(              \
                af[mi], bf[ni], acc[mi][ni], 0, 0, 0);                        \
    __builtin_amdgcn_s_setprio(0);                                            \
    TAIL_STMT;                                                                \
    __builtin_amdgcn_s_barrier();                                             \
  }

  // prologue: tile0 all 4 slabs + tile1 ks0 slabs
  STAGE_A(0, 0);
  STAGE_B(0, 0);
  STAGE_A(1, 0);
  STAGE_B(1, 0);
  STAGE_A(0, 1);
  STAGE_B(0, 1);
  asm volatile("s_waitcnt vmcnt(2)" ::: "memory");  // tile0 landed
  __builtin_amdgcn_s_barrier();

  for (int tt = 0; tt < NT; ++tt) {
    int b = tt & 1;
    PHASE(0, {
      if (tt + 1 < NT) { STAGE_A(1, tt + 1); STAGE_B(1, tt + 1); }
    }, {});
    PHASE(1, {
      if (tt + 2 < NT) { STAGE_A(0, tt + 2); STAGE_B(0, tt + 2); }
    }, {
      if (tt + 2 < NT) {
        asm volatile("s_waitcnt vmcnt(2)" ::: "memory");
      } else if (tt + 1 < NT) {
        asm volatile("s_waitcnt vmcnt(0)" ::: "memory");
      }
    });
  }

#undef PHASE
#undef STAGE_A
#undef STAGE_B

  // epilogue: y = s[m] * acc + bias[n]
#pragma unroll
  for (int mi = 0; mi < 4; ++mi) {
#pragma unroll
    for (int ni = 0; ni < 2; ++ni) {
      int gc = colBase + wc * 64 + ni * 32 + l31;
      float bv = bias[gc];
#pragma unroll
      for (int rg = 0; rg < 16; ++rg) {
        int rowIn = (rg & 3) + 8 * (rg >> 2) + 4 * hi;
        int gr = rowBase + wr * 128 + mi * 32 + rowIn;
        C[(size_t)gr * N_TOT + gc] = (float)acc[mi][ni][rg] * s[gr] + bv;
      }
    }
  }
}

// ---------------- fallback (ws too small): fused bf16 conversion GEMM --------
__global__ void gemm_fused_kernel(const float* __restrict__ A,
                                  const float* __restrict__ W,
                                  const float* __restrict__ bias,
                                  float* __restrict__ C) {
  __shared__ ushort lsA[128 * 32];
  __shared__ ushort lsB[128 * 32];

  int nwg = gridDim.x;
  int bid = blockIdx.x;
  int wg = (bid & 7) * (nwg >> 3) + (bid >> 3);
  const int NBN = N_TOT / 128;
  int bm = wg / NBN;
  int bn = wg % NBN;
  int rowBase = bm * 128;
  int colBase = bn * 128;

  int t = threadIdx.x;
  int lane = t & 63;
  int wave = t >> 6;
  int wm = (wave >> 1) * 64;
  int wn = (wave & 1) * 64;

  f32x4 acc[4][4] = {};

  int srow = t >> 3;
  int scol = (t & 7) * 4;
  int fr = lane & 15;
  int koff = (lane >> 4) * 8;

  for (int k0 = 0; k0 < K_TOT; k0 += 32) {
    float4 va[4], vb[4];
#pragma unroll
    for (int r = 0; r < 4; ++r) {
      va[r] = *(const float4*)&A[(size_t)(rowBase + r * 32 + srow) * K_TOT + k0 + scol];
      vb[r] = *(const float4*)&W[(size_t)(colBase + r * 32 + srow) * K_TOT + k0 + scol];
    }
    __syncthreads();
#pragma unroll
    for (int r = 0; r < 4; ++r) {
      int e = r * 1024 + t * 4;
      ushort4 oa, ob;
      oa.x = f2bf_rne(va[r].x); oa.y = f2bf_rne(va[r].y);
      oa.z = f2bf_rne(va[r].z); oa.w = f2bf_rne(va[r].w);
      ob.x = sgn_bf16(vb[r].x); ob.y = sgn_bf16(vb[r].y);
      ob.z = sgn_bf16(vb[r].z); ob.w = sgn_bf16(vb[r].w);
      *(ushort4*)&lsA[e] = oa;
      *(ushort4*)&lsB[e] = ob;
    }
    __syncthreads();

    bf16x8 af[4], bfr[4];
#pragma unroll
    for (int i = 0; i < 4; ++i)
      af[i] = *(const bf16x8*)&lsA[(wm + i * 16 + fr) * 32 + koff];
#pragma unroll
    for (int j = 0; j < 4; ++j)
      bfr[j] = *(const bf16x8*)&lsB[(wn + j * 16 + fr) * 32 + koff];

#pragma unroll
    for (int i = 0; i < 4; ++i)
#pragma unroll
      for (int j = 0; j < 4; ++j)
        acc[i][j] = __builtin_amdgcn_mfma_f32_16x16x32_bf16(af[i], bfr[j],
                                                            acc[i][j], 0, 0, 0);
  }

  int orow0 = rowBase + wm + ((lane >> 4) << 2);
  int ocol0 = colBase + wn + (lane & 15);
#pragma unroll
  for (int i = 0; i < 4; ++i) {
#pragma unroll
    for (int j = 0; j < 4; ++j) {
      int col = ocol0 + j * 16;
      float bv = bias[col];
#pragma unroll
      for (int rg = 0; rg < 4; ++rg) {
        int row = orow0 + i * 16 + rg;
        C[(size_t)row * N_TOT + col] = acc[i][j][rg] + bv;
      }
    }
  }
}

extern "C" void kernel_launch(void* const* d_in, const int* in_sizes, int n_in,
                              void* d_out, int out_size, void* d_ws,
                              size_t ws_size, hipStream_t stream) {
  const float* x = (const float*)d_in[0];
  const float* W = (const float*)d_in[1];
  const float* b = (const float*)d_in[2];
  float* out = (float*)d_out;

  const size_t xq_bytes = (size_t)M_TOT * K_TOT;           // 33.5 MB
  const size_t wq_bytes = (size_t)N_TOT * K_TOT;           // 67.1 MB
  const size_t need = xq_bytes + wq_bytes + M_TOT * 4;     // ~101 MB

  if (ws_size >= need) {
    char* xq = (char*)d_ws;
    char* wq = xq + xq_bytes;
    float* s = (float*)(wq + wq_bytes);
    quant_x_kernel<<<M_TOT, 256, 0, stream>>>(x, xq, s);
    quant_w_kernel<<<2048, 256, 0, stream>>>(W, wq, (int)(wq_bytes / 4));
    const int nblocks = (M_TOT / BM) * (N_TOT / BN);  // 2048
    gemm_i8_2phase<<<nblocks, 512, 0, stream>>>(xq, wq, s, b, out);
  } else {
    const int nblocks = (M_TOT / 128) * (N_TOT / 128);
    gemm_fused_kernel<<<nblocks, 256, 0, stream>>>(x, W, b, out);
  }
}

// Round 5
// 845.744 us; speedup vs baseline: 1.4236x; 1.0116x over previous
//
#include <hip/hip_runtime.h>
#include <hip/hip_bf16.h>

#define M_TOT 8192
#define N_TOT 16384
#define K_TOT 4096
#define BM 256
#define BN 256
#define BK 64
#define NT (K_TOT / BK)  // 64 K-tiles

typedef int i32x4 __attribute__((ext_vector_type(4)));
typedef int i32x16 __attribute__((ext_vector_type(16)));
typedef __bf16 bf16x8 __attribute__((ext_vector_type(8)));
typedef float f32x4 __attribute__((ext_vector_type(4)));

#define GLOAD_LDS16(g, l)                                                     \
  __builtin_amdgcn_global_load_lds(                                           \
      (__attribute__((address_space(1))) const void*)(g),                     \
      (__attribute__((address_space(3))) void*)(l), 16, 0, 0)

__device__ __forceinline__ ushort f2bf_rne(float f) {
  unsigned u = __float_as_uint(f);
  u += 0x7FFFu + ((u >> 16) & 1u);
  return (ushort)(u >> 16);
}
__device__ __forceinline__ ushort sgn_bf16(float w) {
  return w > 0.f ? (ushort)0x3F80u : (w < 0.f ? (ushort)0xBF80u : (ushort)0u);
}

// ---------------- pass 1a: per-row amax + quantize x to i8 ----------------
__global__ void quant_x_kernel(const float* __restrict__ x,
                               char* __restrict__ xq, float* __restrict__ s) {
  int row = blockIdx.x;
  const float4* xr = (const float4*)(x + (size_t)row * K_TOT);
  int tid = threadIdx.x;
  float4 v[4];
  float amax = 0.f;
#pragma unroll
  for (int j = 0; j < 4; ++j) {
    v[j] = xr[j * 256 + tid];
    amax = fmaxf(amax, fmaxf(fmaxf(fabsf(v[j].x), fabsf(v[j].y)),
                             fmaxf(fabsf(v[j].z), fabsf(v[j].w))));
  }
#pragma unroll
  for (int o = 32; o > 0; o >>= 1) amax = fmaxf(amax, __shfl_xor(amax, o));
  __shared__ float wmax[4];
  if ((tid & 63) == 0) wmax[tid >> 6] = amax;
  __syncthreads();
  amax = fmaxf(fmaxf(wmax[0], wmax[1]), fmaxf(wmax[2], wmax[3]));
  float inv = amax > 0.f ? 127.0f / amax : 0.f;
  if (tid == 0) s[row] = amax * (1.0f / 127.0f);
  int* out = (int*)(xq + (size_t)row * K_TOT);
#pragma unroll
  for (int j = 0; j < 4; ++j) {
    int q0 = max(-127, min(127, __float2int_rn(v[j].x * inv)));
    int q1 = max(-127, min(127, __float2int_rn(v[j].y * inv)));
    int q2 = max(-127, min(127, __float2int_rn(v[j].z * inv)));
    int q3 = max(-127, min(127, __float2int_rn(v[j].w * inv)));
    out[j * 256 + tid] =
        (q0 & 255) | ((q1 & 255) << 8) | ((q2 & 255) << 16) | ((q3 & 255) << 24);
  }
}

// ---------------- pass 1b: W -> sign in i8 ----------------
__global__ void quant_w_kernel(const float* __restrict__ w,
                               char* __restrict__ wq, int n4) {
  int i = blockIdx.x * blockDim.x + threadIdx.x;
  int stride = gridDim.x * blockDim.x;
  for (; i < n4; i += stride) {
    float4 v = ((const float4*)w)[i];
    int q0 = v.x > 0.f ? 1 : (v.x < 0.f ? -1 : 0);
    int q1 = v.y > 0.f ? 1 : (v.y < 0.f ? -1 : 0);
    int q2 = v.z > 0.f ? 1 : (v.z < 0.f ? -1 : 0);
    int q3 = v.w > 0.f ? 1 : (v.w < 0.f ? -1 : 0);
    ((int*)wq)[i] =
        (q0 & 255) | ((q1 & 255) << 8) | ((q2 & 255) << 16) | ((q3 & 255) << 24);
  }
}

// ---------------- pass 2: i8 GEMM, mfma_i32_32x32x32_i8, 4-phase/tile --------
// C[m][n] = s[m] * (sum_k A8[m][k]*W8[n][k]) + bias[n]   (i32 accum, exact)
// 512 threads = 8 waves (2M x 4N); per-wave out 128x64 = 4 m x 2 n of 32x32.
// BK=64 = 2 ks-slices of K=32. LDS: [2 buf][2 ks][2 op][256 x 32B] = 64 KiB.
// Swizzle: 16B chunk c of row r stored at slot c ^ ((r>>2)&1) (both-sides).
//
// 4 phases per tile t (buf b = t&1), A-frags held in regs across ph pairs:
//   ph0 (ks0,n0): read A0-3+B0 [5 rd]; stage Aks1(t+1); bar; 4 MFMA; bar
//   ph1 (ks0,n1): read B1      [1 rd]; stage Bks1(t+1); bar; 4 MFMA; bar
//   ph2 (ks1,n0): read A0-3+B0 [5 rd]; stage Aks0(t+2); bar; 4 MFMA; bar
//   ph3 (ks1,n1): read B1      [1 rd]; stage Bks0(t+2); bar; 4 MFMA;
//                 vmcnt(2) [oldest 4 = tile t+1 complete]; bar
// Race audit (stage slab X only after barrier following drained last read):
//   Aks1(t+1)/Bks1(t+1): other buffer, last read tile t-1 ph2/ph3  -> safe
//   Aks0(t+2): same buf, last read ph0 (drained pre-MFMA, ph0-end bar) -> safe
//   Bks0(t+2): same buf, last read ph1 (drained, ph1-end bar)         -> safe
__global__ __launch_bounds__(512, 2) void gemm_i8_4phase(
    const char* __restrict__ A, const char* __restrict__ B,
    const float* __restrict__ s, const float* __restrict__ bias,
    float* __restrict__ C) {
  __shared__ char lds[2][2][2][8192];  // [buf][ks][op 0=A 1=B][256x32B slab]

  int nwg = gridDim.x;  // 2048, divisible by 8
  int bid = blockIdx.x;
  int wg = (bid & 7) * (nwg >> 3) + (bid >> 3);  // XCD-bijective swizzle
  int bm = wg / (N_TOT / BN);
  int bn = wg % (N_TOT / BN);
  int rowBase = bm * BM;
  int colBase = bn * BN;

  int t = threadIdx.x;
  int lane = t & 63;
  int wave = t >> 6;
  int wr = wave >> 2;  // M half (128)
  int wc = wave & 3;   // N quarter (64)
  int l31 = lane & 31;
  int hi = lane >> 5;

  // staging: thread t owns 16B slot at byte t*16 = (row t>>1, slot-chunk t&1);
  // stored item chunk = (t&1) ^ ((row>>2)&1) = (t&1) ^ ((t>>3)&1)
  int sc = ((t & 1) ^ ((t >> 3) & 1)) * 16;
  const char* gA = A + (size_t)(rowBase + (t >> 1)) * K_TOT + sc;
  const char* gB = B + (size_t)(colBase + (t >> 1)) * K_TOT + sc;
  int lt = t * 16;

  // frag read: chunk wanted = hi, stored at hi ^ ((row>>2)&1); row bases are
  // multiples of 32 so (row>>2)&1 = (lane>>2)&1 -> per-lane constant.
  int csw = (hi ^ ((lane >> 2) & 1)) * 16;
  int aoff = (wr * 128 + l31) * 32 + csw;
  int boff = (wc * 64 + l31) * 32 + csw;

  i32x16 acc[4][2] = {};

#define STAGE_A(ks_, kt_)                                                     \
  GLOAD_LDS16(gA + (size_t)(kt_)*64 + (ks_)*32, &lds[(kt_)&1][ks_][0][lt])
#define STAGE_B(ks_, kt_)                                                     \
  GLOAD_LDS16(gB + (size_t)(kt_)*64 + (ks_)*32, &lds[(kt_)&1][ks_][1][lt])

#define MFMA4(bf_, ni_)                                                       \
  __builtin_amdgcn_s_barrier();                                               \
  __builtin_amdgcn_s_setprio(1);                                              \
  _Pragma("unroll") for (int mi = 0; mi < 4; ++mi)                            \
      acc[mi][ni_] = __builtin_amdgcn_mfma_i32_32x32x32_i8(                   \
          af[mi], bf_, acc[mi][ni_], 0, 0, 0);                                \
  __builtin_amdgcn_s_setprio(0);

  // prologue: tile0 all 4 slabs + tile1 ks0 slabs (FIFO: tile0 oldest)
  STAGE_A(0, 0);
  STAGE_B(0, 0);
  STAGE_A(1, 0);
  STAGE_B(1, 0);
  STAGE_A(0, 1);
  STAGE_B(0, 1);
  asm volatile("s_waitcnt vmcnt(2)" ::: "memory");  // tile0 landed
  __builtin_amdgcn_s_barrier();

  for (int tt = 0; tt < NT; ++tt) {
    int b = tt & 1;
    i32x4 af[4], bf0, bf1;

    // ---- ph0: ks0, n0 ----
    {
      const char* _ab = &lds[b][0][0][0];
      const char* _bb = &lds[b][0][1][0];
#pragma unroll
      for (int mi = 0; mi < 4; ++mi)
        af[mi] = *(const i32x4*)(_ab + aoff + mi * 1024);
      bf0 = *(const i32x4*)(_bb + boff);
      if (tt + 1 < NT) STAGE_A(1, tt + 1);
      MFMA4(bf0, 0);
      __builtin_amdgcn_s_barrier();
    }
    // ---- ph1: ks0, n1 (A frags reused from regs) ----
    {
      const char* _bb = &lds[b][0][1][0];
      bf1 = *(const i32x4*)(_bb + boff + 1024);
      if (tt + 1 < NT) STAGE_B(1, tt + 1);
      MFMA4(bf1, 1);
      __builtin_amdgcn_s_barrier();
    }
    // ---- ph2: ks1, n0 ----
    {
      const char* _ab = &lds[b][1][0][0];
      const char* _bb = &lds[b][1][1][0];
#pragma unroll
      for (int mi = 0; mi < 4; ++mi)
        af[mi] = *(const i32x4*)(_ab + aoff + mi * 1024);
      bf0 = *(const i32x4*)(_bb + boff);
      if (tt + 2 < NT) STAGE_A(0, tt + 2);
      MFMA4(bf0, 0);
      __builtin_amdgcn_s_barrier();
    }
    // ---- ph3: ks1, n1 ----
    {
      const char* _bb = &lds[b][1][1][0];
      bf1 = *(const i32x4*)(_bb + boff + 1024);
      if (tt + 2 < NT) STAGE_B(0, tt + 2);
      MFMA4(bf1, 1);
      if (tt + 2 < NT) {
        asm volatile("s_waitcnt vmcnt(2)" ::: "memory");
      } else if (tt + 1 < NT) {
        asm volatile("s_waitcnt vmcnt(0)" ::: "memory");
      }
      __builtin_amdgcn_s_barrier();
    }
  }

#undef MFMA4
#undef STAGE_A
#undef STAGE_B

  // epilogue: y = s[m] * acc + bias[n]
  // C/D 32x32: col = lane&31, row = (reg&3) + 8*(reg>>2) + 4*(lane>>5)
#pragma unroll
  for (int mi = 0; mi < 4; ++mi) {
#pragma unroll
    for (int ni = 0; ni < 2; ++ni) {
      int gc = colBase + wc * 64 + ni * 32 + l31;
      float bv = bias[gc];
#pragma unroll
      for (int rg = 0; rg < 16; ++rg) {
        int rowIn = (rg & 3) + 8 * (rg >> 2) + 4 * hi;
        int gr = rowBase + wr * 128 + mi * 32 + rowIn;
        C[(size_t)gr * N_TOT + gc] = (float)acc[mi][ni][rg] * s[gr] + bv;
      }
    }
  }
}

// ---------------- fallback (ws too small): fused bf16 conversion GEMM --------
__global__ void gemm_fused_kernel(const float* __restrict__ A,
                                  const float* __restrict__ W,
                                  const float* __restrict__ bias,
                                  float* __restrict__ C) {
  __shared__ ushort lsA[128 * 32];
  __shared__ ushort lsB[128 * 32];

  int nwg = gridDim.x;
  int bid = blockIdx.x;
  int wg = (bid & 7) * (nwg >> 3) + (bid >> 3);
  const int NBN = N_TOT / 128;
  int bm = wg / NBN;
  int bn = wg % NBN;
  int rowBase = bm * 128;
  int colBase = bn * 128;

  int t = threadIdx.x;
  int lane = t & 63;
  int wave = t >> 6;
  int wm = (wave >> 1) * 64;
  int wn = (wave & 1) * 64;

  f32x4 acc[4][4] = {};

  int srow = t >> 3;
  int scol = (t & 7) * 4;
  int fr = lane & 15;
  int koff = (lane >> 4) * 8;

  for (int k0 = 0; k0 < K_TOT; k0 += 32) {
    float4 va[4], vb[4];
#pragma unroll
    for (int r = 0; r < 4; ++r) {
      va[r] = *(const float4*)&A[(size_t)(rowBase + r * 32 + srow) * K_TOT + k0 + scol];
      vb[r] = *(const float4*)&W[(size_t)(colBase + r * 32 + srow) * K_TOT + k0 + scol];
    }
    __syncthreads();
#pragma unroll
    for (int r = 0; r < 4; ++r) {
      int e = r * 1024 + t * 4;
      ushort4 oa, ob;
      oa.x = f2bf_rne(va[r].x); oa.y = f2bf_rne(va[r].y);
      oa.z = f2bf_rne(va[r].z); oa.w = f2bf_rne(va[r].w);
      ob.x = sgn_bf16(vb[r].x); ob.y = sgn_bf16(vb[r].y);
      ob.z = sgn_bf16(vb[r].z); ob.w = sgn_bf16(vb[r].w);
      *(ushort4*)&lsA[e] = oa;
      *(ushort4*)&lsB[e] = ob;
    }
    __syncthreads();

    bf16x8 af[4], bfr[4];
#pragma unroll
    for (int i = 0; i < 4; ++i)
      af[i] = *(const bf16x8*)&lsA[(wm + i * 16 + fr) * 32 + koff];
#pragma unroll
    for (int j = 0; j < 4; ++j)
      bfr[j] = *(const bf16x8*)&lsB[(wn + j * 16 + fr) * 32 + koff];

#pragma unroll
    for (int i = 0; i < 4; ++i)
#pragma unroll
      for (int j = 0; j < 4; ++j)
        acc[i][j] = __builtin_amdgcn_mfma_f32_16x16x32_bf16(af[i], bfr[j],
                                                            acc[i][j], 0, 0, 0);
  }

  int orow0 = rowBase + wm + ((lane >> 4) << 2);
  int ocol0 = colBase + wn + (lane & 15);
#pragma unroll
  for (int i = 0; i < 4; ++i) {
#pragma unroll
    for (int j = 0; j < 4; ++j) {
      int col = ocol0 + j * 16;
      float bv = bias[col];
#pragma unroll
      for (int rg = 0; rg < 4; ++rg) {
        int row = orow0 + i * 16 + rg;
        C[(size_t)row * N_TOT + col] = acc[i][j][rg] + bv;
      }
    }
  }
}

extern "C" void kernel_launch(void* const* d_in, const int* in_sizes, int n_in,
                              void* d_out, int out_size, void* d_ws,
                              size_t ws_size, hipStream_t stream) {
  const float* x = (const float*)d_in[0];
  const float* W = (const float*)d_in[1];
  const float* b = (const float*)d_in[2];
  float* out = (float*)d_out;

  const size_t xq_bytes = (size_t)M_TOT * K_TOT;           // 33.5 MB
  const size_t wq_bytes = (size_t)N_TOT * K_TOT;           // 67.1 MB
  const size_t need = xq_bytes + wq_bytes + M_TOT * 4;     // ~101 MB

  if (ws_size >= need) {
    char* xq = (char*)d_ws;
    char* wq = xq + xq_bytes;
    float* s = (float*)(wq + wq_bytes);
    quant_x_kernel<<<M_TOT, 256, 0, stream>>>(x, xq, s);
    quant_w_kernel<<<2048, 256, 0, stream>>>(W, wq, (int)(wq_bytes / 4));
    const int nblocks = (M_TOT / BM) * (N_TOT / BN);  // 2048
    gemm_i8_4phase<<<nblocks, 512, 0, stream>>>(xq, wq, s, b, out);
  } else {
    const int nblocks = (M_TOT / 128) * (N_TOT / 128);
    gemm_fused_kernel<<<nblocks, 256, 0, stream>>>(x, W, b, out);
  }
}

// Round 6
// 782.811 us; speedup vs baseline: 1.5380x; 1.0804x over previous
//
#include <hip/hip_runtime.h>
#include <hip/hip_bf16.h>

#define M_TOT 8192
#define N_TOT 16384
#define K_TOT 4096
#define BM 128
#define BN 256
#define BK 64
#define NT (K_TOT / BK)  // 64 K-tiles

typedef int i32x4 __attribute__((ext_vector_type(4)));
typedef int i32x16 __attribute__((ext_vector_type(16)));
typedef __bf16 bf16x8 __attribute__((ext_vector_type(8)));
typedef float f32x4 __attribute__((ext_vector_type(4)));

#define GLOAD_LDS16(g, l)                                                     \
  __builtin_amdgcn_global_load_lds(                                           \
      (__attribute__((address_space(1))) const void*)(g),                     \
      (__attribute__((address_space(3))) void*)(l), 16, 0, 0)

__device__ __forceinline__ ushort f2bf_rne(float f) {
  unsigned u = __float_as_uint(f);
  u += 0x7FFFu + ((u >> 16) & 1u);
  return (ushort)(u >> 16);
}
__device__ __forceinline__ ushort sgn_bf16(float w) {
  return w > 0.f ? (ushort)0x3F80u : (w < 0.f ? (ushort)0xBF80u : (ushort)0u);
}

// ---------------- pass 1a: per-row amax + quantize x to i8 ----------------
__global__ void quant_x_kernel(const float* __restrict__ x,
                               char* __restrict__ xq, float* __restrict__ s) {
  int row = blockIdx.x;
  const float4* xr = (const float4*)(x + (size_t)row * K_TOT);
  int tid = threadIdx.x;
  float4 v[4];
  float amax = 0.f;
#pragma unroll
  for (int j = 0; j < 4; ++j) {
    v[j] = xr[j * 256 + tid];
    amax = fmaxf(amax, fmaxf(fmaxf(fabsf(v[j].x), fabsf(v[j].y)),
                             fmaxf(fabsf(v[j].z), fabsf(v[j].w))));
  }
#pragma unroll
  for (int o = 32; o > 0; o >>= 1) amax = fmaxf(amax, __shfl_xor(amax, o));
  __shared__ float wmax[4];
  if ((tid & 63) == 0) wmax[tid >> 6] = amax;
  __syncthreads();
  amax = fmaxf(fmaxf(wmax[0], wmax[1]), fmaxf(wmax[2], wmax[3]));
  float inv = amax > 0.f ? 127.0f / amax : 0.f;
  if (tid == 0) s[row] = amax * (1.0f / 127.0f);
  int* out = (int*)(xq + (size_t)row * K_TOT);
#pragma unroll
  for (int j = 0; j < 4; ++j) {
    int q0 = max(-127, min(127, __float2int_rn(v[j].x * inv)));
    int q1 = max(-127, min(127, __float2int_rn(v[j].y * inv)));
    int q2 = max(-127, min(127, __float2int_rn(v[j].z * inv)));
    int q3 = max(-127, min(127, __float2int_rn(v[j].w * inv)));
    out[j * 256 + tid] =
        (q0 & 255) | ((q1 & 255) << 8) | ((q2 & 255) << 16) | ((q3 & 255) << 24);
  }
}

// ---------------- pass 1b: W -> sign in i8 ----------------
__global__ void quant_w_kernel(const float* __restrict__ w,
                               char* __restrict__ wq, int n4) {
  int i = blockIdx.x * blockDim.x + threadIdx.x;
  int stride = gridDim.x * blockDim.x;
  for (; i < n4; i += stride) {
    float4 v = ((const float4*)w)[i];
    int q0 = v.x > 0.f ? 1 : (v.x < 0.f ? -1 : 0);
    int q1 = v.y > 0.f ? 1 : (v.y < 0.f ? -1 : 0);
    int q2 = v.z > 0.f ? 1 : (v.z < 0.f ? -1 : 0);
    int q3 = v.w > 0.f ? 1 : (v.w < 0.f ? -1 : 0);
    ((int*)wq)[i] =
        (q0 & 255) | ((q1 & 255) << 8) | ((q2 & 255) << 16) | ((q3 & 255) << 24);
  }
}

// ---------------- pass 2: i8 GEMM, 2 blocks/CU, wave-tile 64x64 --------------
// C[m][n] = s[m] * (sum_k A8[m][k]*W8[n][k]) + bias[n]   (i32 accum, exact)
// BM=128 BN=256 BK=64. 512 threads = 8 waves (2M x 4N), wave-tile 64x64 =
// 2x2 of 32x32 -> acc = 64 AGPRs; launch_bounds(512,4) targets <=128 unified
// regs -> 16 waves/CU = TWO blocks/CU (cross-block latency hiding).
// LDS: A[2][128x64B]=16KB + B[2][256x64B]=32KB = 48KB (2 blocks = 96 <=160).
// Layout: 64B rows; 16B chunk c of row r stored at slot c ^ ((r>>1)&3)
// (round-3-proven: 0 bank conflicts; all 8 bank-quads distinct per 8-lane
// group for the 32x32-i8 frag read row=lane&31, chunk=2ks+(lane>>5)).
// gload_lds dest linear; involution applied on the per-lane GLOBAL source.
// Schedule per tile t (buf b=t&1): reads+8 MFMA; bar; STAGE(t+2 -> buf b);
// vmcnt(3) [t+1 landed, t+2 in flight -- never drains to 0]; bar.
__global__ __launch_bounds__(512, 4) void gemm_i8_dual(
    const char* __restrict__ A, const char* __restrict__ B,
    const float* __restrict__ s, const float* __restrict__ bias,
    float* __restrict__ C) {
  __shared__ char ldsA[2][128 * 64];
  __shared__ char ldsB[2][256 * 64];

  // XCD swizzle (4096 blocks): each XCD gets 512 contiguous wg = one bn
  // supertile stripe (8 bn cols x all 64 bm rows) -> A streamed once/XCD,
  // B stripe ~8MB vs 4MB L2 (partial hold).
  int bid = blockIdx.x;
  int wg = (bid & 7) * 512 + (bid >> 3);
  int bnSup = wg >> 9;             // 0..7
  int rem = wg & 511;
  int bm = rem >> 3;               // 0..63
  int bn = bnSup * 8 + (rem & 7);  // 0..63
  int rowBase = bm * BM;
  int colBase = bn * BN;

  int t = threadIdx.x;
  int lane = t & 63;
  int wave = t >> 6;
  int wr = wave >> 2;  // 0..1 -> M half (64)
  int wc = wave & 3;   // 0..3 -> N quarter (64)
  int l31 = lane & 31;
  int hi = lane >> 5;

  // staging: thread t owns dest byte t*16 = (row t>>2, slot t&3);
  // stored chunk = (t&3) ^ ((t>>3)&3). (+128-row gB1 preserves the XOR.)
  int sc = ((t & 3) ^ ((t >> 3) & 3)) * 16;
  const char* gA = A + (size_t)(rowBase + (t >> 2)) * K_TOT + sc;
  const char* gB0 = B + (size_t)(colBase + (t >> 2)) * K_TOT + sc;
  const char* gB1 = gB0 + (size_t)128 * K_TOT;
  int lt = t * 16;

  // frag read: row = base + l31 (bases mult of 32 -> XOR idx = (l31>>1)&3);
  // chunk wanted = 2*ks + hi.
  int rxor = (l31 >> 1) & 3;
  int cs0 = (hi ^ rxor) * 16;        // ks0
  int cs1 = ((2 | hi) ^ rxor) * 16;  // ks1
  int arow = (wr * 64 + l31) * 64;   // + mi*32*64
  int brow = (wc * 64 + l31) * 64;   // + ni*32*64

  i32x16 acc[2][2] = {};

#define STAGE(kt_, buf_)                                                      \
  {                                                                           \
    size_t _o = (size_t)(kt_)*64;                                             \
    GLOAD_LDS16(gA + _o, &ldsA[buf_][lt]);                                    \
    GLOAD_LDS16(gB0 + _o, &ldsB[buf_][lt]);                                   \
    GLOAD_LDS16(gB1 + _o, &ldsB[buf_][8192 + lt]);                            \
  }

  // prologue: tiles 0 and 1
  STAGE(0, 0);
  STAGE(1, 1);
  asm volatile("s_waitcnt vmcnt(3)" ::: "memory");  // tile0 landed
  __builtin_amdgcn_s_barrier();

  for (int tt = 0; tt < NT; ++tt) {
    int b = tt & 1;
    const char* la = &ldsA[b][0];
    const char* lb = &ldsB[b][0];
    i32x4 af[2], bf[2];
    // ---- ks0 ----
    af[0] = *(const i32x4*)(la + arow + cs0);
    af[1] = *(const i32x4*)(la + arow + 2048 + cs0);
    bf[0] = *(const i32x4*)(lb + brow + cs0);
    bf[1] = *(const i32x4*)(lb + brow + 2048 + cs0);
    __builtin_amdgcn_s_setprio(1);
#pragma unroll
    for (int mi = 0; mi < 2; ++mi)
#pragma unroll
      for (int ni = 0; ni < 2; ++ni)
        acc[mi][ni] = __builtin_amdgcn_mfma_i32_32x32x32_i8(af[mi], bf[ni],
                                                            acc[mi][ni], 0, 0, 0);
    __builtin_amdgcn_s_setprio(0);
    // ---- ks1 ----
    af[0] = *(const i32x4*)(la + arow + cs1);
    af[1] = *(const i32x4*)(la + arow + 2048 + cs1);
    bf[0] = *(const i32x4*)(lb + brow + cs1);
    bf[1] = *(const i32x4*)(lb + brow + 2048 + cs1);
    __builtin_amdgcn_s_setprio(1);
#pragma unroll
    for (int mi = 0; mi < 2; ++mi)
#pragma unroll
      for (int ni = 0; ni < 2; ++ni)
        acc[mi][ni] = __builtin_amdgcn_mfma_i32_32x32x32_i8(af[mi], bf[ni],
                                                            acc[mi][ni], 0, 0, 0);
    __builtin_amdgcn_s_setprio(0);

    __builtin_amdgcn_s_barrier();  // all waves done reading buf b
    if (tt + 2 < NT) {
      STAGE(tt + 2, b);            // overwrite buf b for tile t+2
      asm volatile("s_waitcnt vmcnt(3)" ::: "memory");  // tile t+1 landed
    } else if (tt + 1 < NT) {
      asm volatile("s_waitcnt vmcnt(0)" ::: "memory");  // last prefetch landed
    }
    __builtin_amdgcn_s_barrier();  // buf b^1 ready for all waves
  }

#undef STAGE

  // epilogue: y = s[m] * acc + bias[n]
  // C/D 32x32: col = lane&31, row = (reg&3) + 8*(reg>>2) + 4*(lane>>5)
#pragma unroll
  for (int mi = 0; mi < 2; ++mi) {
#pragma unroll
    for (int ni = 0; ni < 2; ++ni) {
      int gc = colBase + wc * 64 + ni * 32 + l31;
      float bv = bias[gc];
#pragma unroll
      for (int rg = 0; rg < 16; ++rg) {
        int rowIn = (rg & 3) + 8 * (rg >> 2) + 4 * hi;
        int gr = rowBase + wr * 64 + mi * 32 + rowIn;
        C[(size_t)gr * N_TOT + gc] = (float)acc[mi][ni][rg] * s[gr] + bv;
      }
    }
  }
}

// ---------------- fallback (ws too small): fused bf16 conversion GEMM --------
__global__ void gemm_fused_kernel(const float* __restrict__ A,
                                  const float* __restrict__ W,
                                  const float* __restrict__ bias,
                                  float* __restrict__ C) {
  __shared__ ushort lsA[128 * 32];
  __shared__ ushort lsB[128 * 32];

  int nwg = gridDim.x;
  int bid = blockIdx.x;
  int wg = (bid & 7) * (nwg >> 3) + (bid >> 3);
  const int NBN = N_TOT / 128;
  int bm = wg / NBN;
  int bn = wg % NBN;
  int rowBase = bm * 128;
  int colBase = bn * 128;

  int t = threadIdx.x;
  int lane = t & 63;
  int wave = t >> 6;
  int wm = (wave >> 1) * 64;
  int wn = (wave & 1) * 64;

  f32x4 acc[4][4] = {};

  int srow = t >> 3;
  int scol = (t & 7) * 4;
  int fr = lane & 15;
  int koff = (lane >> 4) * 8;

  for (int k0 = 0; k0 < K_TOT; k0 += 32) {
    float4 va[4], vb[4];
#pragma unroll
    for (int r = 0; r < 4; ++r) {
      va[r] = *(const float4*)&A[(size_t)(rowBase + r * 32 + srow) * K_TOT + k0 + scol];
      vb[r] = *(const float4*)&W[(size_t)(colBase + r * 32 + srow) * K_TOT + k0 + scol];
    }
    __syncthreads();
#pragma unroll
    for (int r = 0; r < 4; ++r) {
      int e = r * 1024 + t * 4;
      ushort4 oa, ob;
      oa.x = f2bf_rne(va[r].x); oa.y = f2bf_rne(va[r].y);
      oa.z = f2bf_rne(va[r].z); oa.w = f2bf_rne(va[r].w);
      ob.x = sgn_bf16(vb[r].x); ob.y = sgn_bf16(vb[r].y);
      ob.z = sgn_bf16(vb[r].z); ob.w = sgn_bf16(vb[r].w);
      *(ushort4*)&lsA[e] = oa;
      *(ushort4*)&lsB[e] = ob;
    }
    __syncthreads();

    bf16x8 af[4], bfr[4];
#pragma unroll
    for (int i = 0; i < 4; ++i)
      af[i] = *(const bf16x8*)&lsA[(wm + i * 16 + fr) * 32 + koff];
#pragma unroll
    for (int j = 0; j < 4; ++j)
      bfr[j] = *(const bf16x8*)&lsB[(wn + j * 16 + fr) * 32 + koff];

#pragma unroll
    for (int i = 0; i < 4; ++i)
#pragma unroll
      for (int j = 0; j < 4; ++j)
        acc[i][j] = __builtin_amdgcn_mfma_f32_16x16x32_bf16(af[i], bfr[j],
                                                            acc[i][j], 0, 0, 0);
  }

  int orow0 = rowBase + wm + ((lane >> 4) << 2);
  int ocol0 = colBase + wn + (lane & 15);
#pragma unroll
  for (int i = 0; i < 4; ++i) {
#pragma unroll
    for (int j = 0; j < 4; ++j) {
      int col = ocol0 + j * 16;
      float bv = bias[col];
#pragma unroll
      for (int rg = 0; rg < 4; ++rg) {
        int row = orow0 + i * 16 + rg;
        C[(size_t)row * N_TOT + col] = acc[i][j][rg] + bv;
      }
    }
  }
}

extern "C" void kernel_launch(void* const* d_in, const int* in_sizes, int n_in,
                              void* d_out, int out_size, void* d_ws,
                              size_t ws_size, hipStream_t stream) {
  const float* x = (const float*)d_in[0];
  const float* W = (const float*)d_in[1];
  const float* b = (const float*)d_in[2];
  float* out = (float*)d_out;

  const size_t xq_bytes = (size_t)M_TOT * K_TOT;           // 33.5 MB
  const size_t wq_bytes = (size_t)N_TOT * K_TOT;           // 67.1 MB
  const size_t need = xq_bytes + wq_bytes + M_TOT * 4;     // ~101 MB

  if (ws_size >= need) {
    char* xq = (char*)d_ws;
    char* wq = xq + xq_bytes;
    float* s = (float*)(wq + wq_bytes);
    quant_x_kernel<<<M_TOT, 256, 0, stream>>>(x, xq, s);
    quant_w_kernel<<<2048, 256, 0, stream>>>(W, wq, (int)(wq_bytes / 4));
    const int nblocks = (M_TOT / BM) * (N_TOT / BN);  // 4096
    gemm_i8_dual<<<nblocks, 512, 0, stream>>>(xq, wq, s, b, out);
  } else {
    const int nblocks = (M_TOT / 128) * (N_TOT / 128);
    gemm_fused_kernel<<<nblocks, 256, 0, stream>>>(x, W, b, out);
  }
}